// Round 5
// baseline (1400.418 us; speedup 1.0000x reference)
//
#include <hip/hip_runtime.h>
#include <hip/hip_bf16.h>

#define IGNORE_INDEX (-100)

using f32x4  = __attribute__((ext_vector_type(4))) float;
using bf16x8 = __attribute__((ext_vector_type(8))) short;

constexpr int BM = 256, BN = 256;
constexpr int MT = 8;      // m tiles (2048 / 256)
constexpr int NT = 500;    // n tiles for fallback (128000 / 256)
constexpr int NT2 = 1000;  // n tiles for main kernel (128000 / 128)
constexpr int KT32 = 64;   // k tiles of 32 (2048 / 32)
constexpr int SROWS = 2047;
constexpr int DDIM = 2048;

constexpr size_t WS_ACC_BYTES = 16384;
constexpr size_t WS_A_BYTES   = (size_t)2048 * 2048 * 2;
constexpr size_t WS_W_BYTES   = (size_t)128000 * 2048 * 2;
constexpr size_t WS_NEED      = WS_ACC_BYTES + WS_A_BYTES + WS_W_BYTES;

__device__ __forceinline__ unsigned cvt_pk_bf16(float lo, float hi) {
    unsigned r;
    asm("v_cvt_pk_bf16_f32 %0, %1, %2" : "=v"(r) : "v"(lo), "v"(hi));
    return r;
}

__device__ __forceinline__ void gload_lds16(const void* g, void* l) {
    __builtin_amdgcn_global_load_lds(
        (__attribute__((address_space(1))) void*)(g),
        (__attribute__((address_space(3))) void*)(l), 16, 0, 0);
}

// ---------------- prepass: fp32 -> bf16 (RNE) ----------------
__global__ __launch_bounds__(256)
void cvt_f32_bf16(const float* __restrict__ src, unsigned short* __restrict__ dst, size_t n8)
{
    size_t i = (size_t)blockIdx.x * 256 + threadIdx.x;
    const size_t stride = (size_t)gridDim.x * 256;
    for (; i < n8; i += stride) {
        const float4* s = (const float4*)(src + i * 8);
        float4 a = s[0], b = s[1];
        uint4 u;
        u.x = cvt_pk_bf16(a.x, a.y); u.y = cvt_pk_bf16(a.z, a.w);
        u.z = cvt_pk_bf16(b.x, b.y); u.w = cvt_pk_bf16(b.z, b.w);
        ((uint4*)dst)[i] = u;
    }
}

// ---- main fused GEMM + CE epilogue: 256x128 tile, 4 waves, 2 blocks/CU, 3-buf counted-vmcnt ----
__global__ __launch_bounds__(256, 2)
void ce_gemm2b(const unsigned short* __restrict__ Abf,
               const unsigned short* __restrict__ Wbf,
               const float* __restrict__ bias,
               const int* __restrict__ labels,
               float* __restrict__ sumexp,
               float* __restrict__ tgt)
{
    // 3 bufs x (A[256][32] + B[128][32]) bf16 = 3 x 24 KiB = 72 KiB
    __shared__ __align__(16) unsigned short lds[3 * 12288];

    const int bid = blockIdx.x;                 // 8000 blocks, 8000%8==0 -> bijective
    const int L = (bid & 7) * (MT * NT2 / 8) + (bid >> 3);
    const int n_tile = L >> 3;                  // 0..999
    const int m_tile = L & 7;
    const int m_base = m_tile * BM;
    const int n_base = n_tile * 128;

    const int T    = threadIdx.x;               // 0..255
    const int lane = T & 63;
    const int wave = T >> 6;                    // 0..3
    const int wm = wave >> 1;                   // 0..1
    const int wn = wave & 1;                    // 0..1
    const int q = lane & 15;
    const int g = lane >> 4;                    // 0..3
    // chunk-XOR involution over 4 chunks of 8 shorts: phys = g ^ (row&3), row&3 == q&3
    const int cg = ((g ^ (q & 3)) << 3);

    // staging: thread T fills phys slot (row = i*64 + (T>>2), chunk = T&3);
    // logical source chunk = (T&3) ^ ((T>>2)&3)
    const int sch8 = (((T & 3) ^ ((T >> 2) & 3)) << 3);
    const int w512 = wave * 512;                // shorts; lane offset is linear (8 shorts/lane)

    f32x4 acc[8][4];
#pragma unroll
    for (int i = 0; i < 8; ++i)
#pragma unroll
        for (int j = 0; j < 4; ++j)
            acc[i][j] = (f32x4){0.f, 0.f, 0.f, 0.f};

    const unsigned short* Asrc = Abf + (size_t)(m_base + (T >> 2)) * DDIM + sch8;
    const unsigned short* Bsrc = Wbf + (size_t)(n_base + (T >> 2)) * DDIM + sch8;

    // per K-tile: A = 4 wave-instrs (256 rows), B = 2 (128 rows)
    auto STAGE_A2 = [&](int kt, int i0) {       // 2 A-slices
        const int b = (kt % 3) * 12288, kc = kt * 32;
#pragma unroll
        for (int i = 0; i < 2; ++i)
            gload_lds16(Asrc + (size_t)(i0 + i) * 64 * DDIM + kc,
                        &lds[b + (i0 + i) * 2048 + w512]);
    };
    auto STAGE_B1 = [&](int kt, int i0) {       // 1 B-slice
        const int b = (kt % 3) * 12288, kc = kt * 32;
        gload_lds16(Bsrc + (size_t)i0 * 64 * DDIM + kc,
                    &lds[b + 8192 + i0 * 2048 + w512]);
    };

    // prologue: tiles 0 and 1 fully staged (6+6 loads/wave)
    STAGE_A2(0, 0); STAGE_A2(0, 2); STAGE_B1(0, 0); STAGE_B1(0, 1);
    STAGE_A2(1, 0); STAGE_A2(1, 2); STAGE_B1(1, 0); STAGE_B1(1, 1);
    asm volatile("s_waitcnt vmcnt(6)" ::: "memory");   // tile 0 landed
    asm volatile("s_barrier" ::: "memory");

    const int arow = wm * 128 + q;
    const int brow = wn * 64 + q;

    for (int t = 0; t < KT32; ++t) {
        const int rb_ = (t % 3) * 12288;
        const unsigned short* As_ = &lds[rb_];
        const unsigned short* Bs_ = &lds[rb_ + 8192];
        const bool st = (t < KT32 - 2);
        bf16x8 bfr[4], afr[4];

        // ---- phase 0: mf 0..3 (8 ds_reads) ----
#pragma unroll
        for (int nf = 0; nf < 4; ++nf)
            bfr[nf] = *(const bf16x8*)&Bs_[(brow + nf * 16) * 32 + cg];
#pragma unroll
        for (int m = 0; m < 4; ++m)
            afr[m] = *(const bf16x8*)&As_[(arow + m * 16) * 32 + cg];
        if (st) { STAGE_A2(t + 2, 0); STAGE_B1(t + 2, 0); }
        asm volatile("s_waitcnt lgkmcnt(4)" ::: "memory");
        asm volatile("s_barrier" ::: "memory");
        asm volatile("s_waitcnt lgkmcnt(0)" ::: "memory");
        __builtin_amdgcn_s_setprio(1);
#pragma unroll
        for (int m = 0; m < 4; ++m)
#pragma unroll
            for (int nf = 0; nf < 4; ++nf)
                acc[m][nf] = __builtin_amdgcn_mfma_f32_16x16x32_bf16(afr[m], bfr[nf], acc[m][nf], 0, 0, 0);
        __builtin_amdgcn_s_setprio(0);
        asm volatile("s_barrier" ::: "memory");

        // ---- phase 1: mf 4..7 (4 ds_reads, reuse bfr) ----
#pragma unroll
        for (int m = 0; m < 4; ++m)
            afr[m] = *(const bf16x8*)&As_[(arow + (4 + m) * 16) * 32 + cg];
        if (st) { STAGE_A2(t + 2, 2); STAGE_B1(t + 2, 1); }
        asm volatile("s_barrier" ::: "memory");
        asm volatile("s_waitcnt lgkmcnt(0)" ::: "memory");
        __builtin_amdgcn_s_setprio(1);
#pragma unroll
        for (int m = 0; m < 4; ++m)
#pragma unroll
            for (int nf = 0; nf < 4; ++nf)
                acc[4 + m][nf] = __builtin_amdgcn_mfma_f32_16x16x32_bf16(afr[m], bfr[nf], acc[4 + m][nf], 0, 0, 0);
        __builtin_amdgcn_s_setprio(0);
        // counted wait: newest 6 = tile t+2's loads stay in flight; tile t+1 landed
        if (t < KT32 - 2)       asm volatile("s_waitcnt vmcnt(6)" ::: "memory");
        else if (t == KT32 - 2) asm volatile("s_waitcnt vmcnt(0)" ::: "memory");
        asm volatile("s_barrier" ::: "memory");
    }

    // ---- epilogue: bias + exp + row-sum + target gather ----
    const int grow_base = m_base + wm * 128;
    const int gcol_base = n_base + wn * 64;
#pragma unroll
    for (int mf = 0; mf < 8; ++mf) {
        const int rb = grow_base + mf * 16 + g * 4;
        int lbl[4];
#pragma unroll
        for (int r = 0; r < 4; ++r)
            lbl[r] = (rb + r < SROWS) ? labels[rb + r + 1] : -1;
        float rsum[4] = {0.f, 0.f, 0.f, 0.f};
#pragma unroll
        for (int nf = 0; nf < 4; ++nf) {
            const int gc = gcol_base + nf * 16 + q;
            const float bz = bias[gc];
            const f32x4 v = acc[mf][nf];
#pragma unroll
            for (int r = 0; r < 4; ++r) {
                const float s = v[r] + bz;
                if (lbl[r] == gc) atomicAdd(&tgt[rb + r], s);
                rsum[r] += __expf(s);
            }
        }
#pragma unroll
        for (int r = 0; r < 4; ++r) {
#pragma unroll
            for (int off = 1; off < 16; off <<= 1)
                rsum[r] += __shfl_xor(rsum[r], off);
        }
        if (q == 0) {
#pragma unroll
            for (int r = 0; r < 4; ++r)
                if (rb + r < SROWS) atomicAdd(&sumexp[rb + r], rsum[r]);
        }
    }
}

// ---------------- fallback: fp32 in, reg-staged cvt (round-1 kernel) ----------------
__global__ __launch_bounds__(512, 2)
void ce_fused_gemm(const float* __restrict__ emb,
                   const float* __restrict__ W,
                   const float* __restrict__ bias,
                   const int* __restrict__ labels,
                   float* __restrict__ sumexp,
                   float* __restrict__ tgt)
{
    constexpr int BK = 64;
    constexpr int KT = 32;
    __shared__ __align__(16) unsigned short As[2][BM * BK];
    __shared__ __align__(16) unsigned short Bs[2][BN * BK];

    const int bid = blockIdx.x;
    const int L = (bid & 7) * (MT * NT / 8) + (bid >> 3);
    const int n_tile = L >> 3;
    const int m_tile = L & 7;
    const size_t m_base = (size_t)m_tile * BM;
    const size_t n_base = (size_t)n_tile * BN;

    const int tid  = threadIdx.x;
    const int lane = tid & 63;
    const int wave = tid >> 6;
    const int wm = wave >> 2;
    const int wn = wave & 3;
    const int q = lane & 15;
    const int g = lane >> 4;
    const int r0 = tid >> 3;
    const int kg = tid & 7;

    float4 stA[4][2], stB[4][2];
    f32x4 acc[8][4];
#pragma unroll
    for (int i = 0; i < 8; ++i)
#pragma unroll
        for (int j = 0; j < 4; ++j)
            acc[i][j] = (f32x4){0.f, 0.f, 0.f, 0.f};

    const float* Ab = emb + m_base * DDIM + (size_t)kg * 8;
    const float* Bb = W   + n_base * DDIM + (size_t)kg * 8;

#define STAGE_LOAD(kt_) { \
    const size_t ko = (size_t)(kt_) * BK; \
    _Pragma("unroll") \
    for (int p = 0; p < 4; ++p) { \
        const int row = r0 + p * 64; \
        const float4* pa = (const float4*)(Ab + (size_t)row * DDIM + ko); \
        stA[p][0] = pa[0]; stA[p][1] = pa[1]; \
        const float4* pb = (const float4*)(Bb + (size_t)row * DDIM + ko); \
        stB[p][0] = pb[0]; stB[p][1] = pb[1]; \
    } }

#define STAGE_WRITE(bf_) { \
    _Pragma("unroll") \
    for (int p = 0; p < 4; ++p) { \
        const int row = r0 + p * 64; \
        const int sw = (kg * 8) ^ ((row & 7) << 3); \
        uint4 ua; \
        ua.x = cvt_pk_bf16(stA[p][0].x, stA[p][0].y); \
        ua.y = cvt_pk_bf16(stA[p][0].z, stA[p][0].w); \
        ua.z = cvt_pk_bf16(stA[p][1].x, stA[p][1].y); \
        ua.w = cvt_pk_bf16(stA[p][1].z, stA[p][1].w); \
        *(uint4*)&As[bf_][row * BK + sw] = ua; \
        uint4 ub; \
        ub.x = cvt_pk_bf16(stB[p][0].x, stB[p][0].y); \
        ub.y = cvt_pk_bf16(stB[p][0].z, stB[p][0].w); \
        ub.z = cvt_pk_bf16(stB[p][1].x, stB[p][1].y); \
        ub.w = cvt_pk_bf16(stB[p][1].z, stB[p][1].w); \
        *(uint4*)&Bs[bf_][row * BK + sw] = ub; \
    } }

#define COMPUTE(bf_) { \
    _Pragma("unroll") \
    for (int kh = 0; kh < 2; ++kh) { \
        const int c = kh * 32 + g * 8; \
        bf16x8 bfr[4]; \
        _Pragma("unroll") \
        for (int nf = 0; nf < 4; ++nf) { \
            const int rr = wn * 64 + nf * 16 + q; \
            bfr[nf] = *(const bf16x8*)&Bs[bf_][rr * BK + (c ^ ((rr & 7) << 3))]; \
        } \
        _Pragma("unroll") \
        for (int mf = 0; mf < 8; ++mf) { \
            const int rr = wm * 128 + mf * 16 + q; \
            bf16x8 afr = *(const bf16x8*)&As[bf_][rr * BK + (c ^ ((rr & 7) << 3))]; \
            _Pragma("unroll") \
            for (int nf = 0; nf < 4; ++nf) \
                acc[mf][nf] = __builtin_amdgcn_mfma_f32_16x16x32_bf16(afr, bfr[nf], acc[mf][nf], 0, 0, 0); \
        } \
    } }

    STAGE_LOAD(0);
    STAGE_WRITE(0);
    __syncthreads();

    int buf = 0;
    for (int kt = 0; kt < KT; ++kt) {
        if (kt + 1 < KT) STAGE_LOAD(kt + 1);
        COMPUTE(buf);
        if (kt + 1 < KT) STAGE_WRITE(buf ^ 1);
        __syncthreads();
        buf ^= 1;
    }

    const int grow_base = (int)m_base + wm * 128;
    const int gcol_base = (int)n_base + wn * 64;
#pragma unroll
    for (int mf = 0; mf < 8; ++mf) {
        const int rb = grow_base + mf * 16 + g * 4;
        int lbl[4];
#pragma unroll
        for (int r = 0; r < 4; ++r)
            lbl[r] = (rb + r < SROWS) ? labels[rb + r + 1] : -1;
        float rsum[4] = {0.f, 0.f, 0.f, 0.f};
#pragma unroll
        for (int nf = 0; nf < 4; ++nf) {
            const int gc = gcol_base + nf * 16 + q;
            const float bz = bias[gc];
            const f32x4 v = acc[mf][nf];
#pragma unroll
            for (int r = 0; r < 4; ++r) {
                const float s = v[r] + bz;
                if (lbl[r] == gc) atomicAdd(&tgt[rb + r], s);
                rsum[r] += __expf(s);
            }
        }
#pragma unroll
        for (int r = 0; r < 4; ++r) {
#pragma unroll
            for (int off = 1; off < 16; off <<= 1)
                rsum[r] += __shfl_xor(rsum[r], off);
        }
        if (q == 0) {
#pragma unroll
            for (int r = 0; r < 4; ++r)
                if (rb + r < SROWS) atomicAdd(&sumexp[rb + r], rsum[r]);
        }
    }
#undef STAGE_LOAD
#undef STAGE_WRITE
#undef COMPUTE
}

__global__ void ce_finalize(const float* __restrict__ sumexp,
                            const float* __restrict__ tgt,
                            const int* __restrict__ labels,
                            float* __restrict__ out)
{
    const int tid = threadIdx.x;
    float acc = 0.f, cnt = 0.f;
    for (int s = tid; s < SROWS; s += 256) {
        if (labels[s + 1] != IGNORE_INDEX) {
            acc += __logf(sumexp[s]) - tgt[s];
            cnt += 1.f;
        }
    }
#pragma unroll
    for (int off = 32; off > 0; off >>= 1) {
        acc += __shfl_down(acc, off);
        cnt += __shfl_down(cnt, off);
    }
    __shared__ float sa[4], sc[4];
    if ((tid & 63) == 0) { sa[tid >> 6] = acc; sc[tid >> 6] = cnt; }
    __syncthreads();
    if (tid == 0) {
        float a = sa[0] + sa[1] + sa[2] + sa[3];
        float c = sc[0] + sc[1] + sc[2] + sc[3];
        out[0] = a / fmaxf(c, 1.f);
    }
}

extern "C" void kernel_launch(void* const* d_in, const int* in_sizes, int n_in,
                              void* d_out, int out_size, void* d_ws, size_t ws_size,
                              hipStream_t stream)
{
    const float* emb    = (const float*)d_in[1];
    const float* W      = (const float*)d_in[2];
    const float* bias   = (const float*)d_in[3];
    const int*   labels = (const int*)d_in[4];

    float* wsf    = (float*)d_ws;
    float* sumexp = wsf;
    float* tgt    = wsf + 2048;

    hipMemsetAsync(d_ws, 0, WS_ACC_BYTES, stream);

    if (ws_size >= WS_NEED) {
        unsigned short* Abf = (unsigned short*)((char*)d_ws + WS_ACC_BYTES);
        unsigned short* Wbf = (unsigned short*)((char*)d_ws + WS_ACC_BYTES + WS_A_BYTES);
        cvt_f32_bf16<<<dim3(2048), dim3(256), 0, stream>>>(W, Wbf, (size_t)128000 * 2048 / 8);
        cvt_f32_bf16<<<dim3(256),  dim3(256), 0, stream>>>(emb, Abf, (size_t)2048 * 2048 / 8);
        ce_gemm2b<<<dim3(MT * NT2), dim3(256), 0, stream>>>(Abf, Wbf, bias, labels, sumexp, tgt);
    } else {
        ce_fused_gemm<<<dim3(MT * NT), dim3(512), 0, stream>>>(emb, W, bias, labels, sumexp, tgt);
    }
    ce_finalize<<<dim3(1), dim3(256), 0, stream>>>(sumexp, tgt, labels, (float*)d_out);
}

// Round 6
// 1296.012 us; speedup vs baseline: 1.0806x; 1.0806x over previous
//
#include <hip/hip_runtime.h>
#include <hip/hip_bf16.h>

#define IGNORE_INDEX (-100)

using f32x4  = __attribute__((ext_vector_type(4))) float;
using bf16x8 = __attribute__((ext_vector_type(8))) short;

constexpr int BM = 256, BN = 256;
constexpr int MT = 8;      // m tiles (2048 / 256)
constexpr int NT = 500;    // n tiles (128000 / 256)
constexpr int SROWS = 2047;
constexpr int DDIM = 2048;

constexpr size_t WS_ACC_BYTES = 16384;
constexpr size_t WS_A_BYTES   = (size_t)2048 * 2048 * 2;
constexpr size_t WS_W_BYTES   = (size_t)128000 * 2048 * 2;
constexpr size_t WS_NEED      = WS_ACC_BYTES + WS_A_BYTES + WS_W_BYTES;

__device__ __forceinline__ unsigned cvt_pk_bf16(float lo, float hi) {
    unsigned r;
    asm("v_cvt_pk_bf16_f32 %0, %1, %2" : "=v"(r) : "v"(lo), "v"(hi));
    return r;
}

__device__ __forceinline__ void gload_lds16(const void* g, void* l) {
    __builtin_amdgcn_global_load_lds(
        (__attribute__((address_space(1))) void*)(g),
        (__attribute__((address_space(3))) void*)(l), 16, 0, 0);
}

// ---------------- prepass: fp32 -> bf16 (RNE) ----------------
__global__ __launch_bounds__(256)
void cvt_f32_bf16(const float* __restrict__ src, unsigned short* __restrict__ dst, size_t n8)
{
    size_t i = (size_t)blockIdx.x * 256 + threadIdx.x;
    const size_t stride = (size_t)gridDim.x * 256;
    for (; i < n8; i += stride) {
        const float4* s = (const float4*)(src + i * 8);
        float4 a = s[0], b = s[1];
        uint4 u;
        u.x = cvt_pk_bf16(a.x, a.y); u.y = cvt_pk_bf16(a.z, a.w);
        u.z = cvt_pk_bf16(b.x, b.y); u.w = cvt_pk_bf16(b.z, b.w);
        ((uint4*)dst)[i] = u;
    }
}

// ------- main fused GEMM + CE epilogue: kh-major 8-phase schedule (even ds_read load) -------
__global__ __launch_bounds__(512, 2)
void ce_gemm8k(const unsigned short* __restrict__ Abf,
               const unsigned short* __restrict__ Wbf,
               const float* __restrict__ bias,
               const int* __restrict__ labels,
               float* __restrict__ sumexp,
               float* __restrict__ tgt)
{
    // 2 bufs x (A[256][64] + B[256][64]) bf16 = 128 KiB
    __shared__ __align__(16) unsigned short lds[2 * 32768];

    const int bid = blockIdx.x;
    const int L = (bid & 7) * (MT * NT / 8) + (bid >> 3);
    const int n_tile = L >> 3;
    const int m_tile = L & 7;
    const int m_base = m_tile * BM;
    const int n_base = n_tile * BN;

    const int T    = threadIdx.x;
    const int lane = T & 63;
    const int wave = T >> 6;
    const int wm = wave >> 2;   // 0..1
    const int wn = wave & 3;    // 0..3
    const int q = lane & 15;
    const int g = lane >> 4;    // 0..3
    const int rq7 = q & 7;
    // phys chunk offsets (shorts) for logical k-half 0 / 1 (chunk-XOR swizzle, involution)
    const int c0 = ((g    ) ^ rq7) << 3;
    const int c1 = ((4 + g) ^ rq7) << 3;

    // staging: thread T fills phys slot (row = base + T>>3, chunk = T&7);
    // logical source chunk = (T&7) ^ ((T>>3)&7)
    const int srow8 = T >> 3;
    const int sch   = (T & 7) ^ ((T >> 3) & 7);

    f32x4 acc[8][4];
#pragma unroll
    for (int i = 0; i < 8; ++i)
#pragma unroll
        for (int j = 0; j < 4; ++j)
            acc[i][j] = (f32x4){0.f, 0.f, 0.f, 0.f};

    const unsigned short* Asrc = Abf + (size_t)(m_base + srow8) * DDIM + sch * 8;
    const unsigned short* Bsrc = Wbf + (size_t)(n_base + srow8) * DDIM + sch * 8;
    const int wbase = wave * 512;   // shorts

    // one half-tile = 2 gload_lds per wave (128 rows x 64 cols bf16)
    auto STAGE_A = [&](int kt, int h) {
        const int kc = kt * 64; const int b = (kt & 1) * 32768;
#pragma unroll
        for (int i = 0; i < 2; ++i) {
            const int blk = 2 * h + i;
            gload_lds16(Asrc + (size_t)blk * 64 * DDIM + kc, &lds[b + blk * 4096 + wbase]);
        }
    };
    auto STAGE_B = [&](int kt, int h) {
        const int kc = kt * 64; const int b = (kt & 1) * 32768;
#pragma unroll
        for (int i = 0; i < 2; ++i) {
            const int blk = 2 * h + i;
            gload_lds16(Bsrc + (size_t)blk * 64 * DDIM + kc, &lds[b + 16384 + blk * 4096 + wbase]);
        }
    };

    const int arow = wm * 128 + q;
    const int brow = wn * 64 + q;
    bf16x8 bfr[4];   // B frags for current k-half (live 2 phases)

    // PH: one phase. MO = mf row offset (0 or 4), CC = chunk offset (c0/c1),
    // BB = lds base (shorts), RB = read B frags this phase.
#define PH(MO, CC, BB, RB, STAGE_STMT, WAIT_STMT) { \
    const unsigned short* As_ = &lds[BB]; \
    const unsigned short* Bs_ = &lds[(BB) + 16384]; \
    bf16x8 afr[4]; \
    if (RB) { \
        _Pragma("unroll") \
        for (int nf = 0; nf < 4; ++nf) \
            bfr[nf] = *(const bf16x8*)&Bs_[(brow + nf * 16) * 64 + (CC)]; \
    } \
    _Pragma("unroll") \
    for (int m = 0; m < 4; ++m) \
        afr[m] = *(const bf16x8*)&As_[(arow + ((MO) + m) * 16) * 64 + (CC)]; \
    STAGE_STMT; \
    if (RB) asm volatile("s_waitcnt lgkmcnt(4)" ::: "memory"); \
    asm volatile("s_barrier" ::: "memory"); \
    asm volatile("s_waitcnt lgkmcnt(0)" ::: "memory"); \
    __builtin_amdgcn_s_setprio(1); \
    _Pragma("unroll") \
    for (int m = 0; m < 4; ++m) \
        _Pragma("unroll") \
        for (int nf = 0; nf < 4; ++nf) \
            acc[(MO) + m][nf] = __builtin_amdgcn_mfma_f32_16x16x32_bf16(afr[m], bfr[nf], acc[(MO) + m][nf], 0, 0, 0); \
    __builtin_amdgcn_s_setprio(0); \
    WAIT_STMT; \
    asm volatile("s_barrier" ::: "memory"); \
}

    // ---- prologue: tile 0 (buf0) fully + B halves of tile 1 (buf1) ----
    STAGE_A(0, 0); STAGE_A(0, 1); STAGE_B(0, 0); STAGE_B(0, 1);   // 8 loads
    STAGE_B(1, 0); STAGE_B(1, 1);                                 // 4 loads
    asm volatile("s_waitcnt vmcnt(4)" ::: "memory");               // tile 0 landed
    asm volatile("s_barrier" ::: "memory");

    // ---- main loop: 16 iterations x 2 K-tiles; phases kh-major ----
    for (int i = 0; i < 16; ++i) {
        const int t0 = 2 * i, t1 = 2 * i + 1;
        const bool st = (i < 15);
        // tile t0 in buf0 (base 0)
        PH(0, c0, 0, true,  { STAGE_A(t1, 0); }, {});
        PH(4, c0, 0, false, { STAGE_A(t1, 1); }, {});
        PH(0, c1, 0, true,  {}, {});
        PH(4, c1, 0, false, { if (st) { STAGE_B(t0 + 2, 0); STAGE_B(t0 + 2, 1); } },
                 { if (st) { asm volatile("s_waitcnt vmcnt(4)" ::: "memory"); }
                   else    { asm volatile("s_waitcnt vmcnt(0)" ::: "memory"); } });
        // tile t1 in buf1 (base 32768)
        PH(0, c0, 32768, true,  { if (st) STAGE_A(t0 + 2, 0); }, {});
        PH(4, c0, 32768, false, { if (st) STAGE_A(t0 + 2, 1); }, {});
        PH(0, c1, 32768, true,  {}, {});
        PH(4, c1, 32768, false, { if (st) { STAGE_B(t1 + 2, 0); STAGE_B(t1 + 2, 1); } },
                     { if (st) { asm volatile("s_waitcnt vmcnt(4)" ::: "memory"); } });
    }
#undef PH

    // ---- epilogue: bias + exp + row-sum + target gather ----
    const int grow_base = m_base + wm * 128;
    const int gcol_base = n_base + wn * 64;
#pragma unroll
    for (int mf = 0; mf < 8; ++mf) {
        const int rb = grow_base + mf * 16 + g * 4;
        int lbl[4];
#pragma unroll
        for (int r = 0; r < 4; ++r)
            lbl[r] = (rb + r < SROWS) ? labels[rb + r + 1] : -1;
        float rsum[4] = {0.f, 0.f, 0.f, 0.f};
#pragma unroll
        for (int nf = 0; nf < 4; ++nf) {
            const int gc = gcol_base + nf * 16 + q;
            const float bz = bias[gc];
            const f32x4 v = acc[mf][nf];
#pragma unroll
            for (int r = 0; r < 4; ++r) {
                const float s = v[r] + bz;
                if (lbl[r] == gc) atomicAdd(&tgt[rb + r], s);
                rsum[r] += __expf(s);
            }
        }
#pragma unroll
        for (int r = 0; r < 4; ++r) {
#pragma unroll
            for (int off = 1; off < 16; off <<= 1)
                rsum[r] += __shfl_xor(rsum[r], off);
        }
        if (q == 0) {
#pragma unroll
            for (int r = 0; r < 4; ++r)
                if (rb + r < SROWS) atomicAdd(&sumexp[rb + r], rsum[r]);
        }
    }
}

// ---------------- fallback: fp32 in, reg-staged cvt (round-1 kernel) ----------------
__global__ __launch_bounds__(512, 2)
void ce_fused_gemm(const float* __restrict__ emb,
                   const float* __restrict__ W,
                   const float* __restrict__ bias,
                   const int* __restrict__ labels,
                   float* __restrict__ sumexp,
                   float* __restrict__ tgt)
{
    constexpr int BK = 64;
    constexpr int KT = 32;
    __shared__ __align__(16) unsigned short As[2][BM * BK];
    __shared__ __align__(16) unsigned short Bs[2][BN * BK];

    const int bid = blockIdx.x;
    const int L = (bid & 7) * (MT * NT / 8) + (bid >> 3);
    const int n_tile = L >> 3;
    const int m_tile = L & 7;
    const size_t m_base = (size_t)m_tile * BM;
    const size_t n_base = (size_t)n_tile * BN;

    const int tid  = threadIdx.x;
    const int lane = tid & 63;
    const int wave = tid >> 6;
    const int wm = wave >> 2;
    const int wn = wave & 3;
    const int q = lane & 15;
    const int g = lane >> 4;
    const int r0 = tid >> 3;
    const int kg = tid & 7;

    float4 stA[4][2], stB[4][2];
    f32x4 acc[8][4];
#pragma unroll
    for (int i = 0; i < 8; ++i)
#pragma unroll
        for (int j = 0; j < 4; ++j)
            acc[i][j] = (f32x4){0.f, 0.f, 0.f, 0.f};

    const float* Ab = emb + m_base * DDIM + (size_t)kg * 8;
    const float* Bb = W   + n_base * DDIM + (size_t)kg * 8;

#define STAGE_LOAD(kt_) { \
    const size_t ko = (size_t)(kt_) * BK; \
    _Pragma("unroll") \
    for (int p = 0; p < 4; ++p) { \
        const int row = r0 + p * 64; \
        const float4* pa = (const float4*)(Ab + (size_t)row * DDIM + ko); \
        stA[p][0] = pa[0]; stA[p][1] = pa[1]; \
        const float4* pb = (const float4*)(Bb + (size_t)row * DDIM + ko); \
        stB[p][0] = pb[0]; stB[p][1] = pb[1]; \
    } }

#define STAGE_WRITE(bf_) { \
    _Pragma("unroll") \
    for (int p = 0; p < 4; ++p) { \
        const int row = r0 + p * 64; \
        const int sw = (kg * 8) ^ ((row & 7) << 3); \
        uint4 ua; \
        ua.x = cvt_pk_bf16(stA[p][0].x, stA[p][0].y); \
        ua.y = cvt_pk_bf16(stA[p][0].z, stA[p][0].w); \
        ua.z = cvt_pk_bf16(stA[p][1].x, stA[p][1].y); \
        ua.w = cvt_pk_bf16(stA[p][1].z, stA[p][1].w); \
        *(uint4*)&As[bf_][row * BK + sw] = ua; \
        uint4 ub; \
        ub.x = cvt_pk_bf16(stB[p][0].x, stB[p][0].y); \
        ub.y = cvt_pk_bf16(stB[p][0].z, stB[p][0].w); \
        ub.z = cvt_pk_bf16(stB[p][1].x, stB[p][1].y); \
        ub.w = cvt_pk_bf16(stB[p][1].z, stB[p][1].w); \
        *(uint4*)&Bs[bf_][row * BK + sw] = ub; \
    } }

#define COMPUTE(bf_) { \
    _Pragma("unroll") \
    for (int kh = 0; kh < 2; ++kh) { \
        const int c = kh * 32 + g * 8; \
        bf16x8 bfr[4]; \
        _Pragma("unroll") \
        for (int nf = 0; nf < 4; ++nf) { \
            const int rr = wn * 64 + nf * 16 + q; \
            bfr[nf] = *(const bf16x8*)&Bs[bf_][rr * BK + (c ^ ((rr & 7) << 3))]; \
        } \
        _Pragma("unroll") \
        for (int mf = 0; mf < 8; ++mf) { \
            const int rr = wm * 128 + mf * 16 + q; \
            bf16x8 afr = *(const bf16x8*)&As[bf_][rr * BK + (c ^ ((rr & 7) << 3))]; \
            _Pragma("unroll") \
            for (int nf = 0; nf < 4; ++nf) \
                acc[mf][nf] = __builtin_amdgcn_mfma_f32_16x16x32_bf16(afr, bfr[nf], acc[mf][nf], 0, 0, 0); \
        } \
    } }

    STAGE_LOAD(0);
    STAGE_WRITE(0);
    __syncthreads();

    int buf = 0;
    for (int kt = 0; kt < KT; ++kt) {
        if (kt + 1 < KT) STAGE_LOAD(kt + 1);
        COMPUTE(buf);
        if (kt + 1 < KT) STAGE_WRITE(buf ^ 1);
        __syncthreads();
        buf ^= 1;
    }

    const int grow_base = (int)m_base + wm * 128;
    const int gcol_base = (int)n_base + wn * 64;
#pragma unroll
    for (int mf = 0; mf < 8; ++mf) {
        const int rb = grow_base + mf * 16 + g * 4;
        int lbl[4];
#pragma unroll
        for (int r = 0; r < 4; ++r)
            lbl[r] = (rb + r < SROWS) ? labels[rb + r + 1] : -1;
        float rsum[4] = {0.f, 0.f, 0.f, 0.f};
#pragma unroll
        for (int nf = 0; nf < 4; ++nf) {
            const int gc = gcol_base + nf * 16 + q;
            const float bz = bias[gc];
            const f32x4 v = acc[mf][nf];
#pragma unroll
            for (int r = 0; r < 4; ++r) {
                const float s = v[r] + bz;
                if (lbl[r] == gc) atomicAdd(&tgt[rb + r], s);
                rsum[r] += __expf(s);
            }
        }
#pragma unroll
        for (int r = 0; r < 4; ++r) {
#pragma unroll
            for (int off = 1; off < 16; off <<= 1)
                rsum[r] += __shfl_xor(rsum[r], off);
        }
        if (q == 0) {
#pragma unroll
            for (int r = 0; r < 4; ++r)
                if (rb + r < SROWS) atomicAdd(&sumexp[rb + r], rsum[r]);
        }
    }
#undef STAGE_LOAD
#undef STAGE_WRITE
#undef COMPUTE
}

__global__ void ce_finalize(const float* __restrict__ sumexp,
                            const float* __restrict__ tgt,
                            const int* __restrict__ labels,
                            float* __restrict__ out)
{
    const int tid = threadIdx.x;
    float acc = 0.f, cnt = 0.f;
    for (int s = tid; s < SROWS; s += 256) {
        if (labels[s + 1] != IGNORE_INDEX) {
            acc += __logf(sumexp[s]) - tgt[s];
            cnt += 1.f;
        }
    }
#pragma unroll
    for (int off = 32; off > 0; off >>= 1) {
        acc += __shfl_down(acc, off);
        cnt += __shfl_down(cnt, off);
    }
    __shared__ float sa[4], sc[4];
    if ((tid & 63) == 0) { sa[tid >> 6] = acc; sc[tid >> 6] = cnt; }
    __syncthreads();
    if (tid == 0) {
        float a = sa[0] + sa[1] + sa[2] + sa[3];
        float c = sc[0] + sc[1] + sc[2] + sc[3];
        out[0] = a / fmaxf(c, 1.f);
    }
}

extern "C" void kernel_launch(void* const* d_in, const int* in_sizes, int n_in,
                              void* d_out, int out_size, void* d_ws, size_t ws_size,
                              hipStream_t stream)
{
    const float* emb    = (const float*)d_in[1];
    const float* W      = (const float*)d_in[2];
    const float* bias   = (const float*)d_in[3];
    const int*   labels = (const int*)d_in[4];

    float* wsf    = (float*)d_ws;
    float* sumexp = wsf;
    float* tgt    = wsf + 2048;

    hipMemsetAsync(d_ws, 0, WS_ACC_BYTES, stream);

    if (ws_size >= WS_NEED) {
        unsigned short* Abf = (unsigned short*)((char*)d_ws + WS_ACC_BYTES);
        unsigned short* Wbf = (unsigned short*)((char*)d_ws + WS_ACC_BYTES + WS_A_BYTES);
        cvt_f32_bf16<<<dim3(2048), dim3(256), 0, stream>>>(W, Wbf, (size_t)128000 * 2048 / 8);
        cvt_f32_bf16<<<dim3(256),  dim3(256), 0, stream>>>(emb, Abf, (size_t)2048 * 2048 / 8);
        ce_gemm8k<<<dim3(MT * NT), dim3(512), 0, stream>>>(Abf, Wbf, bias, labels, sumexp, tgt);
    } else {
        ce_fused_gemm<<<dim3(MT * NT), dim3(512), 0, stream>>>(emb, W, bias, labels, sumexp, tgt);
    }
    ce_finalize<<<dim3(1), dim3(256), 0, stream>>>(sumexp, tgt, labels, (float*)d_out);
}